// Round 1
// baseline (3136.797 us; speedup 1.0000x reference)
//
#include <hip/hip_runtime.h>
#include <hip/hip_bf16.h>

#define C 128

// ---------------------------------------------------------------------------
// zero the per-node edge counters
__global__ void zero_cnt_kernel(int* __restrict__ cnt, int n) {
    int i = blockIdx.x * blockDim.x + threadIdx.x;
    if (i < n) cnt[i] = 0;
}

// count in-degree (edges only; self-loop accounted as +1 later)
__global__ void count_kernel(const int* __restrict__ dst, int* __restrict__ cnt, int E) {
    int e = blockIdx.x * blockDim.x + threadIdx.x;
    if (e < E) atomicAdd(&cnt[dst[e]], 1);
}

// single-block exclusive scan over cnt[0..n) -> offsets/cursor; dinv = rsqrt(cnt+1)
__global__ void scan_kernel(const int* __restrict__ cnt, int* __restrict__ offsets,
                            int* __restrict__ cursor, float* __restrict__ dinv, int n) {
    __shared__ int sums[256];
    int tid = threadIdx.x;
    int chunk = (n + 255) / 256;
    int begin = tid * chunk;
    int end = begin + chunk; if (end > n) end = n;
    if (begin > n) begin = n;
    int s = 0;
    for (int i = begin; i < end; ++i) s += cnt[i];
    sums[tid] = s;
    __syncthreads();
    // Hillis-Steele inclusive scan over the 256 partials
    for (int off = 1; off < 256; off <<= 1) {
        int v = 0;
        if (tid >= off) v = sums[tid - off];
        __syncthreads();
        if (tid >= off) sums[tid] += v;
        __syncthreads();
    }
    int run = (tid == 0) ? 0 : sums[tid - 1];
    for (int i = begin; i < end; ++i) {
        offsets[i] = run;
        cursor[i]  = run;
        dinv[i]    = rsqrtf((float)(cnt[i] + 1));
        run += cnt[i];
    }
    if (tid == 255) offsets[n] = sums[255];
}

// counting-sort scatter: sorted_src holds src ids grouped by dst (CSR)
__global__ void scatter_kernel(const int* __restrict__ src, const int* __restrict__ dst,
                               int* __restrict__ cursor, int* __restrict__ sorted_src, int E) {
    int e = blockIdx.x * blockDim.x + threadIdx.x;
    if (e < E) {
        int d = dst[e];
        int pos = atomicAdd(&cursor[d], 1);
        sorted_src[pos] = src[e];
    }
}

// hidden = coeffs[0] * x
__global__ void init_hidden_kernel(const float* __restrict__ x, const float* __restrict__ coeffs,
                                   float* __restrict__ hidden, int total) {
    int i = blockIdx.x * blockDim.x + threadIdx.x;
    if (i < total) hidden[i] = coeffs[0] * x[i];
}

// one propagation step, fused hidden accumulation.
// block = 256 threads = 2 nodes x 128 channels
__global__ void prop_kernel(const float* __restrict__ xin, float* __restrict__ xout,
                            float* __restrict__ hidden, const float* __restrict__ coeffs, int k,
                            const int* __restrict__ offsets, const int* __restrict__ srcs,
                            const float* __restrict__ dinv, int n) {
    int c = threadIdx.x & (C - 1);
    int v = blockIdx.x * 2 + (threadIdx.x >> 7);
    if (v >= n) return;
    float gamma = coeffs[k];
    int beg = offsets[v];
    int end = offsets[v + 1];
    float acc = 0.0f;
    for (int e = beg; e < end; ++e) {
        int s = srcs[e];
        acc += xin[(size_t)s * C + c] * dinv[s];
    }
    float dv = dinv[v];
    size_t idx = (size_t)v * C + c;
    float val = dv * acc + dv * dv * xin[idx];   // self-loop: norm = dinv[v]^2
    xout[idx] = val;
    hidden[idx] += gamma * val;
}

extern "C" void kernel_launch(void* const* d_in, const int* in_sizes, int n_in,
                              void* d_out, int out_size, void* d_ws, size_t ws_size,
                              hipStream_t stream) {
    const float* x      = (const float*)d_in[0];
    const float* coeffs = (const float*)d_in[1];
    const int*   edge   = (const int*)d_in[2];

    const int N = in_sizes[0] / C;          // 50000
    const int K = in_sizes[1] - 1;          // 10
    const int E = in_sizes[2] / 2;          // 1,600,000
    const int* src = edge;
    const int* dst = edge + E;
    float* hidden = (float*)d_out;

    // workspace carve-up (256B aligned): ~58.4 MB total
    char* ws = (char*)d_ws;
    auto alloc = [&](size_t bytes) -> void* {
        void* p = (void*)ws;
        ws += (bytes + 255) & ~(size_t)255;
        return p;
    };
    int*   cnt        = (int*)alloc((size_t)N * 4);
    int*   offsets    = (int*)alloc((size_t)(N + 1) * 4);
    int*   cursor     = (int*)alloc((size_t)N * 4);
    int*   sorted_src = (int*)alloc((size_t)E * 4);
    float* dinv       = (float*)alloc((size_t)N * 4);
    float* buf0       = (float*)alloc((size_t)N * C * 4);
    float* buf1       = (float*)alloc((size_t)N * C * 4);

    const int B = 256;
    zero_cnt_kernel<<<(N + B - 1) / B, B, 0, stream>>>(cnt, N);
    count_kernel<<<(E + B - 1) / B, B, 0, stream>>>(dst, cnt, E);
    scan_kernel<<<1, 256, 0, stream>>>(cnt, offsets, cursor, dinv, N);
    scatter_kernel<<<(E + B - 1) / B, B, 0, stream>>>(src, dst, cursor, sorted_src, E);
    init_hidden_kernel<<<((size_t)N * C + B - 1) / B, B, 0, stream>>>(x, coeffs, hidden, N * C);

    const float* xin = x;
    float* xout = buf0;
    for (int k = 1; k <= K; ++k) {
        prop_kernel<<<(N + 1) / 2, B, 0, stream>>>(xin, xout, hidden, coeffs, k,
                                                   offsets, sorted_src, dinv, N);
        xin  = xout;
        xout = (xout == buf0) ? buf1 : buf0;
    }
}

// Round 2
// 1073.937 us; speedup vs baseline: 2.9208x; 2.9208x over previous
//
#include <hip/hip_runtime.h>
#include <hip/hip_bf16.h>
#include <hip/hip_fp16.h>

#define C 128
#define C2 64   // half2 elements per row

// ---------------------------------------------------------------------------
__global__ void zero_cnt_kernel(int* __restrict__ cnt, int n) {
    int i = blockIdx.x * blockDim.x + threadIdx.x;
    if (i < n) cnt[i] = 0;
}

__global__ void count_kernel(const int* __restrict__ dst, int* __restrict__ cnt, int E) {
    int e = blockIdx.x * blockDim.x + threadIdx.x;
    if (e < E) atomicAdd(&cnt[dst[e]], 1);
}

// single-block exclusive scan over cnt[0..n) -> offsets/cursor; dinv = rsqrt(cnt+1)
__global__ void scan_kernel(const int* __restrict__ cnt, int* __restrict__ offsets,
                            int* __restrict__ cursor, float* __restrict__ dinv, int n) {
    __shared__ int sums[256];
    int tid = threadIdx.x;
    int chunk = (n + 255) / 256;
    int begin = tid * chunk;
    int end = begin + chunk; if (end > n) end = n;
    if (begin > n) begin = n;
    int s = 0;
    for (int i = begin; i < end; ++i) s += cnt[i];
    sums[tid] = s;
    __syncthreads();
    for (int off = 1; off < 256; off <<= 1) {
        int v = 0;
        if (tid >= off) v = sums[tid - off];
        __syncthreads();
        if (tid >= off) sums[tid] += v;
        __syncthreads();
    }
    int run = (tid == 0) ? 0 : sums[tid - 1];
    for (int i = begin; i < end; ++i) {
        offsets[i] = run;
        cursor[i]  = run;
        dinv[i]    = rsqrtf((float)(cnt[i] + 1));
        run += cnt[i];
    }
    if (tid == 255) offsets[n] = sums[255];
}

__global__ void scatter_kernel(const int* __restrict__ src, const int* __restrict__ dst,
                               int* __restrict__ cursor, int* __restrict__ sorted_src, int E) {
    int e = blockIdx.x * blockDim.x + threadIdx.x;
    if (e < E) {
        int d = dst[e];
        int pos = atomicAdd(&cursor[d], 1);
        sorted_src[pos] = src[e];
    }
}

// hidden = coeffs[0]*x (fp32), y0 = half2(dinv[v]*x) — one thread per half2 elem
__global__ void init_kernel(const float* __restrict__ x, const float* __restrict__ coeffs,
                            const float* __restrict__ dinv, float2* __restrict__ hidden,
                            __half2* __restrict__ y0, int total2 /* = N*C2 */) {
    int i = blockIdx.x * blockDim.x + threadIdx.x;
    if (i >= total2) return;
    int v = i >> 6;  // i / C2
    float dv = dinv[v];
    float2 xv = ((const float2*)x)[i];
    float g0 = coeffs[0];
    hidden[i] = make_float2(g0 * xv.x, g0 * xv.y);
    y0[i] = __floats2half2_rn(dv * xv.x, dv * xv.y);
}

// one propagation step on y = D^-1/2 x, fused hidden accumulation.
// block = 256 threads = 4 nodes x 64 lanes; lane owns 2 channels (half2)
__global__ __launch_bounds__(256)
void prop_kernel(const __half2* __restrict__ yin, __half2* __restrict__ yout,
                 float2* __restrict__ hidden, const float* __restrict__ coeffs, int k,
                 const int* __restrict__ offsets, const int* __restrict__ srcs,
                 const float* __restrict__ dinv, int n) {
    int lane = threadIdx.x & 63;
    int v = blockIdx.x * 4 + (threadIdx.x >> 6);
    if (v >= n) return;
    int beg = offsets[v];
    int end = offsets[v + 1];
    float ax0 = 0.f, ay0 = 0.f, ax1 = 0.f, ay1 = 0.f;
    float ax2 = 0.f, ay2 = 0.f, ax3 = 0.f, ay3 = 0.f;
    int e = beg;
    for (; e + 4 <= end; e += 4) {
        int s0 = srcs[e], s1 = srcs[e + 1], s2 = srcs[e + 2], s3 = srcs[e + 3];
        float2 f0 = __half22float2(yin[(size_t)s0 * C2 + lane]);
        float2 f1 = __half22float2(yin[(size_t)s1 * C2 + lane]);
        float2 f2 = __half22float2(yin[(size_t)s2 * C2 + lane]);
        float2 f3 = __half22float2(yin[(size_t)s3 * C2 + lane]);
        ax0 += f0.x; ay0 += f0.y;
        ax1 += f1.x; ay1 += f1.y;
        ax2 += f2.x; ay2 += f2.y;
        ax3 += f3.x; ay3 += f3.y;
    }
    for (; e < end; ++e) {
        int s = srcs[e];
        float2 f = __half22float2(yin[(size_t)s * C2 + lane]);
        ax0 += f.x; ay0 += f.y;
    }
    size_t idx = (size_t)v * C2 + lane;
    float2 self = __half22float2(yin[idx]);
    float sx = (ax0 + ax1) + (ax2 + ax3) + self.x;
    float sy = (ay0 + ay1) + (ay2 + ay3) + self.y;
    float dv = dinv[v];
    float xnx = dv * sx;           // xn = dinv[v] * (sum_{s in N(v)} y[s] + y[v])
    float xny = dv * sy;
    float gamma = coeffs[k];
    float2 h = hidden[idx];
    h.x += gamma * xnx;
    h.y += gamma * xny;
    hidden[idx] = h;
    yout[idx] = __floats2half2_rn(dv * xnx, dv * xny);   // yn = dinv[v] * xn
}

extern "C" void kernel_launch(void* const* d_in, const int* in_sizes, int n_in,
                              void* d_out, int out_size, void* d_ws, size_t ws_size,
                              hipStream_t stream) {
    const float* x      = (const float*)d_in[0];
    const float* coeffs = (const float*)d_in[1];
    const int*   edge   = (const int*)d_in[2];

    const int N = in_sizes[0] / C;          // 50000
    const int K = in_sizes[1] - 1;          // 10
    const int E = in_sizes[2] / 2;          // 1,600,000
    const int* src = edge;
    const int* dst = edge + E;
    float2* hidden = (float2*)d_out;

    char* ws = (char*)d_ws;
    auto alloc = [&](size_t bytes) -> void* {
        void* p = (void*)ws;
        ws += (bytes + 255) & ~(size_t)255;
        return p;
    };
    int*     cnt        = (int*)alloc((size_t)N * 4);
    int*     offsets    = (int*)alloc((size_t)(N + 1) * 4);
    int*     cursor     = (int*)alloc((size_t)N * 4);
    int*     sorted_src = (int*)alloc((size_t)E * 4);
    float*   dinv       = (float*)alloc((size_t)N * 4);
    __half2* buf0       = (__half2*)alloc((size_t)N * C2 * 4);
    __half2* buf1       = (__half2*)alloc((size_t)N * C2 * 4);

    const int B = 256;
    zero_cnt_kernel<<<(N + B - 1) / B, B, 0, stream>>>(cnt, N);
    count_kernel<<<(E + B - 1) / B, B, 0, stream>>>(dst, cnt, E);
    scan_kernel<<<1, 256, 0, stream>>>(cnt, offsets, cursor, dinv, N);
    scatter_kernel<<<(E + B - 1) / B, B, 0, stream>>>(src, dst, cursor, sorted_src, E);
    init_kernel<<<((size_t)N * C2 + B - 1) / B, B, 0, stream>>>(x, coeffs, dinv, hidden, buf0, N * C2);

    const __half2* yin = buf0;
    __half2* yout = buf1;
    for (int k = 1; k <= K; ++k) {
        prop_kernel<<<(N + 3) / 4, B, 0, stream>>>(yin, yout, hidden, coeffs, k,
                                                   offsets, sorted_src, dinv, N);
        yin  = yout;
        yout = (yout == buf0) ? buf1 : buf0;
    }
}

// Round 3
// 1070.982 us; speedup vs baseline: 2.9289x; 1.0028x over previous
//
#include <hip/hip_runtime.h>
#include <hip/hip_fp16.h>

#define C 128
#define C2 64   // half2 per row
#define C4 32   // half4 / float4 per row
#define NBUCK 256

// ---------------------------------------------------------------------------
__global__ void zero_cnt_kernel(int* __restrict__ cnt, int n) {
    int i = blockIdx.x * blockDim.x + threadIdx.x;
    if (i < n) cnt[i] = 0;
}

__global__ void count_kernel(const int* __restrict__ dst, int* __restrict__ cnt, int E) {
    int e = blockIdx.x * blockDim.x + threadIdx.x;
    if (e < E) atomicAdd(&cnt[dst[e]], 1);
}

// ---- 3-phase parallel exclusive scan of cnt[0..n) --------------------------
// phase A: per-block (256 elems) reduce -> psum[b]
__global__ void scan_reduce_kernel(const int* __restrict__ cnt, int* __restrict__ psum, int n) {
    __shared__ int s[256];
    int t = threadIdx.x;
    int i = blockIdx.x * 256 + t;
    s[t] = (i < n) ? cnt[i] : 0;
    __syncthreads();
    for (int off = 128; off > 0; off >>= 1) {
        if (t < off) s[t] += s[t + off];
        __syncthreads();
    }
    if (t == 0) psum[blockIdx.x] = s[0];
}

// phase B: 1 block — exclusive scan of psum[0..nb) -> bpre; offsets[n] = total
__global__ void scan_partials_kernel(const int* __restrict__ psum, int* __restrict__ bpre,
                                     int* __restrict__ offsets, int n, int nb) {
    __shared__ int s[256];
    int t = threadIdx.x;
    s[t] = (t < nb) ? psum[t] : 0;
    __syncthreads();
    for (int off = 1; off < 256; off <<= 1) {
        int v = 0;
        if (t >= off) v = s[t - off];
        __syncthreads();
        if (t >= off) s[t] += v;
        __syncthreads();
    }
    bpre[t] = (t == 0) ? 0 : s[t - 1];
    if (t == 255) offsets[n] = s[255];
}

// phase C: per-block scan + apply -> offsets/cursor/dinv
__global__ void scan_apply_kernel(const int* __restrict__ cnt, const int* __restrict__ bpre,
                                  int* __restrict__ offsets, int* __restrict__ cursor,
                                  float* __restrict__ dinv, int n) {
    __shared__ int s[256];
    int t = threadIdx.x;
    int i = blockIdx.x * 256 + t;
    int c = (i < n) ? cnt[i] : 0;
    s[t] = c;
    __syncthreads();
    for (int off = 1; off < 256; off <<= 1) {
        int v = 0;
        if (t >= off) v = s[t - off];
        __syncthreads();
        if (t >= off) s[t] += v;
        __syncthreads();
    }
    if (i < n) {
        int excl = bpre[blockIdx.x] + s[t] - c;
        offsets[i] = excl;
        cursor[i]  = excl;
        dinv[i]    = rsqrtf((float)(c + 1));
    }
}

// ---- degree bucket sort -> perm (nodes in ascending-degree order) ----------
__global__ void hist_zero_kernel(int* __restrict__ hist) { hist[threadIdx.x] = 0; }

__global__ void hist_kernel(const int* __restrict__ cnt, int* __restrict__ hist, int n) {
    int i = blockIdx.x * blockDim.x + threadIdx.x;
    if (i < n) {
        int d = cnt[i]; if (d > NBUCK - 1) d = NBUCK - 1;
        atomicAdd(&hist[d], 1);
    }
}

__global__ void hist_scan_kernel(const int* __restrict__ hist, int* __restrict__ bcur) {
    __shared__ int s[256];
    int t = threadIdx.x;
    s[t] = hist[t];
    __syncthreads();
    for (int off = 1; off < 256; off <<= 1) {
        int v = 0;
        if (t >= off) v = s[t - off];
        __syncthreads();
        if (t >= off) s[t] += v;
        __syncthreads();
    }
    bcur[t] = (t == 0) ? 0 : s[t - 1];
}

__global__ void perm_kernel(const int* __restrict__ cnt, int* __restrict__ bcur,
                            int* __restrict__ perm, int n) {
    int i = blockIdx.x * blockDim.x + threadIdx.x;
    if (i < n) {
        int d = cnt[i]; if (d > NBUCK - 1) d = NBUCK - 1;
        int pos = atomicAdd(&bcur[d], 1);
        perm[pos] = i;
    }
}

// ---- counting-sort scatter: CSR edge array ---------------------------------
__global__ void scatter_kernel(const int* __restrict__ src, const int* __restrict__ dst,
                               int* __restrict__ cursor, int* __restrict__ sorted_src, int E) {
    int e = blockIdx.x * blockDim.x + threadIdx.x;
    if (e < E) {
        int d = dst[e];
        int pos = atomicAdd(&cursor[d], 1);
        sorted_src[pos] = src[e];
    }
}

// hidden = coeffs[0]*x (fp32), y0 = half2(dinv[v]*x)
__global__ void init_kernel(const float* __restrict__ x, const float* __restrict__ coeffs,
                            const float* __restrict__ dinv, float2* __restrict__ hidden,
                            __half2* __restrict__ y0, int total2) {
    int i = blockIdx.x * blockDim.x + threadIdx.x;
    if (i >= total2) return;
    int v = i >> 6;  // i / C2
    float dv = dinv[v];
    float2 xv = ((const float2*)x)[i];
    float g0 = coeffs[0];
    hidden[i] = make_float2(g0 * xv.x, g0 * xv.y);
    y0[i] = __floats2half2_rn(dv * xv.x, dv * xv.y);
}

// ---------------------------------------------------------------------------
__device__ __forceinline__ float4 h4_to_f4(uint2 u) {
    __half2 p = *reinterpret_cast<__half2*>(&u.x);
    __half2 q = *reinterpret_cast<__half2*>(&u.y);
    float2 f = __half22float2(p);
    float2 g = __half22float2(q);
    return make_float4(f.x, f.y, g.x, g.y);
}

// one propagation step. block = 256 thr = 4 waves = 8 nodes (half-wave/node).
// lane j in [0,32): half4 (4 channels). nodes taken in degree-sorted order.
__global__ __launch_bounds__(256)
void prop_kernel(const __half2* __restrict__ yin, __half2* __restrict__ yout,
                 float4* __restrict__ hidden, const float* __restrict__ coeffs, int k,
                 const int* __restrict__ offsets, const int* __restrict__ srcs,
                 const float* __restrict__ dinv, const int* __restrict__ perm, int n) {
    int lane = threadIdx.x & 63;
    int j = lane & 31;
    int slot = blockIdx.x * 8 + ((threadIdx.x >> 6) << 1) + (lane >> 5);
    if (slot >= n) return;
    int v = perm[slot];
    int beg = offsets[v];
    int end = offsets[v + 1];

    float4 a0 = {0,0,0,0}, a1 = {0,0,0,0}, a2 = {0,0,0,0}, a3 = {0,0,0,0};
    int e = beg;
    for (; e + 4 <= end; e += 4) {
        int s0 = srcs[e], s1 = srcs[e + 1], s2 = srcs[e + 2], s3 = srcs[e + 3];
        uint2 u0 = ((const uint2*)(yin + (size_t)s0 * C2))[j];
        uint2 u1 = ((const uint2*)(yin + (size_t)s1 * C2))[j];
        uint2 u2 = ((const uint2*)(yin + (size_t)s2 * C2))[j];
        uint2 u3 = ((const uint2*)(yin + (size_t)s3 * C2))[j];
        float4 f0 = h4_to_f4(u0), f1 = h4_to_f4(u1), f2 = h4_to_f4(u2), f3 = h4_to_f4(u3);
        a0.x += f0.x; a0.y += f0.y; a0.z += f0.z; a0.w += f0.w;
        a1.x += f1.x; a1.y += f1.y; a1.z += f1.z; a1.w += f1.w;
        a2.x += f2.x; a2.y += f2.y; a2.z += f2.z; a2.w += f2.w;
        a3.x += f3.x; a3.y += f3.y; a3.z += f3.z; a3.w += f3.w;
    }
    for (; e < end; ++e) {
        int s = srcs[e];
        float4 f = h4_to_f4(((const uint2*)(yin + (size_t)s * C2))[j]);
        a0.x += f.x; a0.y += f.y; a0.z += f.z; a0.w += f.w;
    }
    float4 self = h4_to_f4(((const uint2*)(yin + (size_t)v * C2))[j]);
    float sx = (a0.x + a1.x) + (a2.x + a3.x) + self.x;
    float sy = (a0.y + a1.y) + (a2.y + a3.y) + self.y;
    float sz = (a0.z + a1.z) + (a2.z + a3.z) + self.z;
    float sw = (a0.w + a1.w) + (a2.w + a3.w) + self.w;
    float dv = dinv[v];
    float xnx = dv * sx, xny = dv * sy, xnz = dv * sz, xnw = dv * sw;
    float g = coeffs[k];
    size_t hidx = (size_t)v * C4 + j;
    float4 h = hidden[hidx];
    h.x += g * xnx; h.y += g * xny; h.z += g * xnz; h.w += g * xnw;
    hidden[hidx] = h;
    __half2 p = __floats2half2_rn(dv * xnx, dv * xny);
    __half2 q = __floats2half2_rn(dv * xnz, dv * xnw);
    uint2 u;
    u.x = *reinterpret_cast<unsigned int*>(&p);
    u.y = *reinterpret_cast<unsigned int*>(&q);
    ((uint2*)(yout + (size_t)v * C2))[j] = u;
}

extern "C" void kernel_launch(void* const* d_in, const int* in_sizes, int n_in,
                              void* d_out, int out_size, void* d_ws, size_t ws_size,
                              hipStream_t stream) {
    const float* x      = (const float*)d_in[0];
    const float* coeffs = (const float*)d_in[1];
    const int*   edge   = (const int*)d_in[2];

    const int N = in_sizes[0] / C;          // 50000
    const int K = in_sizes[1] - 1;          // 10
    const int E = in_sizes[2] / 2;          // 1,600,000
    const int* src = edge;
    const int* dst = edge + E;

    char* ws = (char*)d_ws;
    auto alloc = [&](size_t bytes) -> void* {
        void* p = (void*)ws;
        ws += (bytes + 255) & ~(size_t)255;
        return p;
    };
    int*     cnt        = (int*)alloc((size_t)N * 4);
    int*     offsets    = (int*)alloc((size_t)(N + 1) * 4);
    int*     cursor     = (int*)alloc((size_t)N * 4);
    int*     sorted_src = (int*)alloc((size_t)E * 4);
    float*   dinv       = (float*)alloc((size_t)N * 4);
    int*     psum       = (int*)alloc(256 * 4);
    int*     bpre       = (int*)alloc(256 * 4);
    int*     hist       = (int*)alloc(NBUCK * 4);
    int*     bcur       = (int*)alloc(NBUCK * 4);
    int*     perm       = (int*)alloc((size_t)N * 4);
    __half2* buf0       = (__half2*)alloc((size_t)N * C2 * 4);
    __half2* buf1       = (__half2*)alloc((size_t)N * C2 * 4);

    const int B = 256;
    const int nb = (N + 255) / 256;   // 196 scan blocks (must be <= 256)

    zero_cnt_kernel<<<(N + B - 1) / B, B, 0, stream>>>(cnt, N);
    count_kernel<<<(E + B - 1) / B, B, 0, stream>>>(dst, cnt, E);

    scan_reduce_kernel<<<nb, 256, 0, stream>>>(cnt, psum, N);
    scan_partials_kernel<<<1, 256, 0, stream>>>(psum, bpre, offsets, N, nb);
    scan_apply_kernel<<<nb, 256, 0, stream>>>(cnt, bpre, offsets, cursor, dinv, N);

    hist_zero_kernel<<<1, NBUCK, 0, stream>>>(hist);
    hist_kernel<<<(N + B - 1) / B, B, 0, stream>>>(cnt, hist, N);
    hist_scan_kernel<<<1, NBUCK, 0, stream>>>(hist, bcur);
    perm_kernel<<<(N + B - 1) / B, B, 0, stream>>>(cnt, bcur, perm, N);

    scatter_kernel<<<(E + B - 1) / B, B, 0, stream>>>(src, dst, cursor, sorted_src, E);
    init_kernel<<<((size_t)N * C2 + B - 1) / B, B, 0, stream>>>(x, coeffs, dinv,
                                                                (float2*)d_out, buf0, N * C2);

    const __half2* yin = buf0;
    __half2* yout = buf1;
    for (int k = 1; k <= K; ++k) {
        prop_kernel<<<(N + 7) / 8, B, 0, stream>>>(yin, yout, (float4*)d_out, coeffs, k,
                                                   offsets, sorted_src, dinv, perm, N);
        yin  = yout;
        yout = (yout == buf0) ? buf1 : buf0;
    }
}